// Round 15
// baseline (297.895 us; speedup 1.0000x reference)
//
#include <hip/hip_runtime.h>
#include <math.h>

#define BB 64
#define TT 8192
#define DD 128
#define RPT 64                   // rows per tile
#define NT 8                     // tiles per block
#define RPBLK (RPT * NT)         // 512 rows per block
#define NBLK (BB * TT / RPBLK)   // 1024 blocks
#define BPB (TT / RPBLK)         // 16 blocks per batch row

typedef float f32x4 __attribute__((ext_vector_type(4)));
typedef __bf16 bf16x4 __attribute__((ext_vector_type(4)));
typedef __bf16 bf16x8 __attribute__((ext_vector_type(8)));

__device__ __forceinline__ float fast_tanh(float x) {
    float t = __expf(2.f * x);
    return 1.f - 2.f * __builtin_amdgcn_rcpf(t + 1.f);
}

// u = 32-bit word holding two bf16: low 16 bits = element i, high = element i+1
__device__ __forceinline__ float bf_at_lo16(unsigned u) { return __uint_as_float(u << 16); }
__device__ __forceinline__ float bf_at_hi16(unsigned u) { return __uint_as_float(u & 0xffff0000u); }

// ---------------------------------------------------------------------------
// Kernel 0: V_w f32 -> bf16, PRE-SWIZZLED in ws: (r,c) -> r*128 + (c^((r&7)<<3))
// ---------------------------------------------------------------------------
__global__ __launch_bounds__(256) void convw_kernel(const float* __restrict__ Vw,
                                                    __bf16* __restrict__ Vw_bf) {
    const int i = blockIdx.x * 256 + threadIdx.x; // 0 .. 16383
    const int r = i >> 7, cidx = i & 127;
    Vw_bf[r * DD + (cidx ^ ((r & 7) << 3))] = (__bf16)Vw[i];
}

// ---------------------------------------------------------------------------
// Kernel 1: fkp[b,o] = dot(Wa_w[o,:], h_tm1[b,:]) + Wa_b[o]
// ---------------------------------------------------------------------------
__global__ __launch_bounds__(DD) void fkprime_kernel(
    const float* __restrict__ Waw, const float* __restrict__ Wab,
    const float* __restrict__ h_tm1, float* __restrict__ fkp) {
    const int b = blockIdx.x;
    const int o = threadIdx.x;
    const float* __restrict__ w = Waw + o * DD;
    const float* __restrict__ h = h_tm1 + b * DD;
    float a0 = 0.f, a1 = 0.f, a2 = 0.f, a3 = 0.f;
#pragma unroll
    for (int d = 0; d < DD; d += 4) {
        float4 w4 = *reinterpret_cast<const float4*>(w + d);
        a0 = fmaf(w4.x, h[d + 0], a0);
        a1 = fmaf(w4.y, h[d + 1], a1);
        a2 = fmaf(w4.z, h[d + 2], a2);
        a3 = fmaf(w4.w, h[d + 3], a3);
    }
    fkp[b * DD + o] = (a0 + a1) + (a2 + a3) + Wab[o];
}

// ---------------------------------------------------------------------------
// Kernel 2: fused scores + e' + z-partial. Per-wave dataflow (no in-loop
// barriers). H tile bf16 16 KB single-buffer (reg-staged), V_w 32 KB via DMA
// -> 50 KB LDS -> 3 blocks/CU. waves_per_eu(3,3) pins occupancy so the
// compiler uses the full VGPR budget and keeps the prefetch loads early.
// ---------------------------------------------------------------------------
__global__ __launch_bounds__(256)
__attribute__((amdgpu_waves_per_eu(3, 3)))
void beta_z_kernel(
    const float* __restrict__ H, const __bf16* __restrict__ Vw_bf,
    const float* __restrict__ Vb, const float* __restrict__ fkp,
    const float* __restrict__ vvec, const float* __restrict__ cptr,
    const int* __restrict__ mask,
    float* __restrict__ eout,      // d_out beta region (e' before normalize)
    float* __restrict__ zpart) {   // [NBLK][DD]
    const int tid  = threadIdx.x;
    const int wv   = tid >> 6;
    const int lane = tid & 63;
    const int cl   = lane & 15;
    const int kg   = lane >> 4;
    const int base_row = blockIdx.x * RPBLK;
    const int b    = base_row >> 13; // 512 | 8192 so block is one b

    __shared__ __align__(16) char s_vw[DD * DD * 2];  // 32 KB bf16 V_w (pre-swz)
    __shared__ __align__(16) char s_h[RPT * DD * 2];  // 16 KB bf16 H tile (swz)
    __shared__ float s_z[4][DD];                      // 2 KB

    // ---- prologue: V_w DMA (linear dest; ws copy pre-swizzled) ----
    {
        const char* __restrict__ wg = (const char*)Vw_bf;
#pragma unroll
        for (int i = 0; i < 8; ++i) {
            __builtin_amdgcn_global_load_lds(
                (const void*)(wg + wv * 8192 + i * 1024 + lane * 16),
                (void*)(s_vw + wv * 8192 + i * 1024), 16, 0, 0);
        }
    }
    // ---- stage tile 0 (own 16 rows): f32 loads -> cvt -> swizzled write ----
    float4 hreg[8];
    {
        const float4* __restrict__ H4 =
            reinterpret_cast<const float4*>(H + (size_t)(base_row + wv * 16) * DD);
#pragma unroll
        for (int i = 0; i < 8; ++i) hreg[i] = H4[i * 64 + lane];
#pragma unroll
        for (int i = 0; i < 8; ++i) {
            bf16x4 r;
            r[0] = (__bf16)hreg[i].x; r[1] = (__bf16)hreg[i].y;
            r[2] = (__bf16)hreg[i].z; r[3] = (__bf16)hreg[i].w;
            const int off = wv * 4096 + (i * 64 + lane) * 8; // byte in 16 KB tile
            const int row = off >> 8;                        // 256 B per bf16 row
            *reinterpret_cast<bf16x4*>(s_h + (off ^ ((row & 7) << 4))) = r;
        }
    }
    __syncthreads();  // drains V_w DMA vmcnt + tile-0 writes

    // hoisted per-lane epilogue constants
    const float cval = cptr[0];
    float biasv[8], vvv[8];
#pragma unroll
    for (int nt = 0; nt < 8; ++nt) {
        const int col = nt * 16 + cl;
        biasv[nt] = Vb[col] + fkp[b * DD + col];
        vvv[nt]   = vvec[col];
    }

    const int ra   = wv * 16 + cl;
    const int swzA = (cl & 7) << 4;  // (ra&7)<<4, wv*16 ≡ 0 mod 8
    float za0 = 0.f, za1 = 0.f;      // z accumulators, d = 2*lane, 2*lane+1

    for (int t = 0; t < NT; ++t) {
        const int grow0 = base_row + t * RPT + wv * 16;

        // ---- prefetch next tile's f32 rows (uses are at loop bottom) ----
        if (t + 1 < NT) {
            const float4* __restrict__ Hn = reinterpret_cast<const float4*>(
                H + (size_t)(grow0 + RPT) * DD);
#pragma unroll
            for (int i = 0; i < 8; ++i) hreg[i] = Hn[i * 64 + lane];
        }
        const float mfl = (float)mask[grow0 + cl];

        // ---- A-frags from bf16 LDS (own rows) ----
        bf16x8 af[4];
#pragma unroll
        for (int kk = 0; kk < 4; ++kk) {
            const int abyte = ra * 256 + kk * 64 + kg * 16;
            af[kk] = *reinterpret_cast<const bf16x8*>(s_h + (abyte ^ swzA));
        }

        // ---- GEMM: own 16 rows x 128 cols ----
        f32x4 acc[8];
#pragma unroll
        for (int nt = 0; nt < 8; ++nt) acc[nt] = (f32x4){0.f, 0.f, 0.f, 0.f};
#pragma unroll
        for (int kk = 0; kk < 4; ++kk) {
#pragma unroll
            for (int nt = 0; nt < 8; ++nt) {
                const int rb    = nt * 16 + cl;
                const int bbyte = (rb * 256 + kk * 64 + kg * 16) ^ ((rb & 7) << 4);
                bf16x8 bfr = *reinterpret_cast<const bf16x8*>(s_vw + bbyte);
                acc[nt] = __builtin_amdgcn_mfma_f32_16x16x32_bf16(af[kk], bfr, acc[nt], 0, 0, 0);
            }
        }

        // ---- epilogue: tanh, v-weighted row-sum, butterfly, e' ----
        float part[4] = {0.f, 0.f, 0.f, 0.f};
#pragma unroll
        for (int nt = 0; nt < 8; ++nt) {
#pragma unroll
            for (int j = 0; j < 4; ++j)
                part[j] = fmaf(fast_tanh(acc[nt][j] + biasv[nt]), vvv[nt], part[j]);
        }
#pragma unroll
        for (int off = 1; off < 16; off <<= 1) {
#pragma unroll
            for (int j = 0; j < 4; ++j) part[j] += __shfl_xor(part[j], off);
        }
        float epj[4];
#pragma unroll
        for (int j = 0; j < 4; ++j) {
            const float mv = __shfl(mfl, kg * 4 + j);
            const float x  = fminf(fmaxf(cval + part[j], -15.f), 15.f);
            epj[j] = __expf(x * mv - 15.f) * mv;
        }
        if (cl == 0) {
#pragma unroll
            for (int j = 0; j < 4; ++j) eout[grow0 + kg * 4 + j] = epj[j];
        }

        // ---- z-accumulate own 16 rows from bf16 LDS ----
#pragma unroll
        for (int r = 0; r < 16; ++r) {
            const float epr = __shfl(epj[r & 3], (r >> 2) << 4);
            const unsigned hv = *reinterpret_cast<const unsigned*>(
                s_h + (((wv * 16 + r) * 256 + lane * 4) ^ ((r & 7) << 4)));
            za0 = fmaf(epr, bf_at_lo16(hv), za0);  // d = 2*lane
            za1 = fmaf(epr, bf_at_hi16(hv), za1);  // d = 2*lane+1
        }

        // ---- write next tile into own rows (after z reads; same-wave order) ----
        if (t + 1 < NT) {
#pragma unroll
            for (int i = 0; i < 8; ++i) {
                bf16x4 r;
                r[0] = (__bf16)hreg[i].x; r[1] = (__bf16)hreg[i].y;
                r[2] = (__bf16)hreg[i].z; r[3] = (__bf16)hreg[i].w;
                const int off = wv * 4096 + (i * 64 + lane) * 8;
                const int row = off >> 8;
                *reinterpret_cast<bf16x4*>(s_h + (off ^ ((row & 7) << 4))) = r;
            }
        }
    }

    // ---- final z-partial combine (one barrier) ----
    s_z[wv][2 * lane]     = za0;
    s_z[wv][2 * lane + 1] = za1;
    __syncthreads();
    if (tid < DD) {
        zpart[(size_t)blockIdx.x * DD + tid] =
            (s_z[0][tid] + s_z[1][tid]) + (s_z[2][tid] + s_z[3][tid]);
    }
}

// ---------------------------------------------------------------------------
// Kernel 3: per-b denom = sum(e') + 1e-6 * e^{gmax-15}; normalize beta in place.
// e^{gmax-15} = any_masked ? max(max e', e^-15) : max e'
// ---------------------------------------------------------------------------
__global__ __launch_bounds__(256) void denom_kernel(
    float* __restrict__ eout, const int* __restrict__ mask,
    float* __restrict__ denom) {
    const int b = blockIdx.x, tid = threadIdx.x;
    float* __restrict__ e = eout + (size_t)b * TT;
    const int* __restrict__ mrow = mask + (size_t)b * TT;
    __shared__ float sE[256], sM[256];
    __shared__ int sA[256];

    float E = 0.f, M = 0.f;
    int any0 = 0;
    for (int t = tid; t < TT; t += 256) {
        float ep = e[t];
        E += ep;
        M = fmaxf(M, ep);
        any0 |= (mrow[t] == 0);
    }
    sE[tid] = E; sM[tid] = M; sA[tid] = any0;
    __syncthreads();
    for (int s = 128; s > 0; s >>= 1) {
        if (tid < s) {
            sE[tid] += sE[tid + s];
            sM[tid] = fmaxf(sM[tid], sM[tid + s]);
            sA[tid] |= sA[tid + s];
        }
        __syncthreads();
    }
    const float scale = sA[0] ? fmaxf(sM[0], 3.0590232e-7f /*e^-15*/) : sM[0];
    const float dn = sE[0] + 1e-6f * scale;
    if (tid == 0) denom[b] = dn;
    const float inv = 1.f / dn;
    for (int t = tid; t < TT; t += 256) e[t] *= inv;
}

// ---------------------------------------------------------------------------
// Kernel 4: z[b,d] = (sum_c zpart[b*BPB+c][d]) / denom[b]
// ---------------------------------------------------------------------------
__global__ __launch_bounds__(256) void zfinal_kernel(
    const float* __restrict__ zpart, const float* __restrict__ denom,
    float* __restrict__ out_z) {
    const int idx = blockIdx.x * 256 + threadIdx.x; // 0 .. B*D-1
    const int b = idx >> 7, d = idx & 127;
    const float* __restrict__ zp = zpart + (size_t)b * BPB * DD + d;
    float s = 0.f;
#pragma unroll
    for (int cc = 0; cc < BPB; ++cc) s += zp[cc * DD];
    out_z[idx] = s / denom[b];
}

// ---------------------------------------------------------------------------
extern "C" void kernel_launch(void* const* d_in, const int* in_sizes, int n_in,
                              void* d_out, int out_size, void* d_ws, size_t ws_size,
                              hipStream_t stream) {
    const float* H     = (const float*)d_in[0]; // [B,T,D] f32
    const int*   mask  = (const int*)d_in[1];   // [B,T] int32
    const float* h_tm1 = (const float*)d_in[2]; // [B,D] f32
    const float* V_w   = (const float*)d_in[3]; // [D,D] f32
    const float* V_b   = (const float*)d_in[4]; // [D] f32
    const float* Wa_w  = (const float*)d_in[5]; // [D,D] f32
    const float* Wa_b  = (const float*)d_in[6]; // [D] f32
    const float* v     = (const float*)d_in[7]; // [D] f32
    const float* c     = (const float*)d_in[8]; // [1] f32

    float* out_z    = (float*)d_out;           // B*D f32
    float* out_beta = (float*)d_out + BB * DD; // B*T f32

    float* ws     = (float*)d_ws;
    float* fkp    = ws;                       // B*D     =   8192 f32
    float* zpart  = fkp + BB * DD;            // NBLK*DD = 131072 f32
    float* denom  = zpart + NBLK * DD;        // BB      =     64 f32
    __bf16* Vw_bf = (__bf16*)(denom + BB);    // D*D bf16 (pre-swizzled)

    convw_kernel<<<(DD * DD) / 256, 256, 0, stream>>>(V_w, Vw_bf);
    fkprime_kernel<<<BB, DD, 0, stream>>>(Wa_w, Wa_b, h_tm1, fkp);
    beta_z_kernel<<<NBLK, 256, 0, stream>>>(H, Vw_bf, V_b, fkp, v, c, mask,
                                            out_beta, zpart);
    denom_kernel<<<BB, 256, 0, stream>>>(out_beta, mask, denom);
    zfinal_kernel<<<(BB * DD) / 256, 256, 0, stream>>>(zpart, denom, out_z);
}

// Round 16
// 81.042 us; speedup vs baseline: 3.6758x; 3.6758x over previous
//
#include <hip/hip_runtime.h>
#include <math.h>

#define BB 64
#define TT 8192
#define DD 128
#define RPT 64                   // rows per tile
#define NT 16                    // tiles per block
#define RPBLK (RPT * NT)         // 1024 rows per block
#define NBLK (BB * TT / RPBLK)   // 512 blocks
#define BPB (TT / RPBLK)         // 8 blocks per batch row

typedef float f32x4 __attribute__((ext_vector_type(4)));
typedef __bf16 bf16x4 __attribute__((ext_vector_type(4)));
typedef __bf16 bf16x8 __attribute__((ext_vector_type(8)));

__device__ __forceinline__ float fast_tanh(float x) {
    float t = __expf(2.f * x);
    return 1.f - 2.f * __builtin_amdgcn_rcpf(t + 1.f);
}

// u = 32-bit word holding two bf16: low 16 bits = element i, high = element i+1
__device__ __forceinline__ float bf_at_lo16(unsigned u) { return __uint_as_float(u << 16); }
__device__ __forceinline__ float bf_at_hi16(unsigned u) { return __uint_as_float(u & 0xffff0000u); }

// ---------------------------------------------------------------------------
// Kernel 1 (fused prep): convw (V_w f32->bf16 pre-swizzled) + fkprime.
// grid(BB=64), block(256). Block b: all 256 threads convert 256 V_w elements;
// threads 0..127 also compute fkp[b,:].
// ---------------------------------------------------------------------------
__global__ __launch_bounds__(256) void prep_kernel(
    const float* __restrict__ Vw, const float* __restrict__ Waw,
    const float* __restrict__ Wab, const float* __restrict__ h_tm1,
    __bf16* __restrict__ Vw_bf, float* __restrict__ fkp) {
    const int b = blockIdx.x, tid = threadIdx.x;
    const int i = b * 256 + tid;               // 0 .. 16383
    const int r = i >> 7, cidx = i & 127;
    Vw_bf[r * DD + (cidx ^ ((r & 7) << 3))] = (__bf16)Vw[i];

    if (tid < DD) {
        const float* __restrict__ w = Waw + tid * DD;
        const float* __restrict__ h = h_tm1 + b * DD;
        float a0 = 0.f, a1 = 0.f, a2 = 0.f, a3 = 0.f;
#pragma unroll
        for (int d = 0; d < DD; d += 4) {
            float4 w4 = *reinterpret_cast<const float4*>(w + d);
            a0 = fmaf(w4.x, h[d + 0], a0);
            a1 = fmaf(w4.y, h[d + 1], a1);
            a2 = fmaf(w4.z, h[d + 2], a2);
            a3 = fmaf(w4.w, h[d + 3], a3);
        }
        fkp[b * DD + tid] = (a0 + a1) + (a2 + a3) + Wab[tid];
    }
}

// ---------------------------------------------------------------------------
// Kernel 2: fused scores + e' + z. Lockstep double-buffered bf16 H tiles
// (R11-proven), V_w via global_load_lds. z accumulated from the bf16
// A-fragment registers (R14-proven reconstruction) -> no z LDS phase, no
// s_ep, ONE barrier per tile. 16 tiles/block. 66 KB LDS -> 2 blocks/CU.
// ---------------------------------------------------------------------------
__global__ __launch_bounds__(256, 2) void beta_z_kernel(
    const float* __restrict__ H, const __bf16* __restrict__ Vw_bf,
    const float* __restrict__ Vb, const float* __restrict__ fkp,
    const float* __restrict__ vvec, const float* __restrict__ cptr,
    const int* __restrict__ mask,
    float* __restrict__ eout,      // d_out beta region (e' before normalize)
    float* __restrict__ zpart) {   // [NBLK][DD]
    const int tid  = threadIdx.x;
    const int wv   = tid >> 6;
    const int lane = tid & 63;
    const int cl   = lane & 15;
    const int kg   = lane >> 4;
    const int base_row = blockIdx.x * RPBLK;
    const int b    = base_row >> 13; // 1024 | 8192 so block is one b

    __shared__ __align__(16) char s_vw[DD * DD * 2];     // 32 KB bf16 V_w (pre-swz)
    __shared__ __align__(16) char s_h[2][RPT * DD * 2];  // 2 x 16 KB bf16 H tiles
    __shared__ float s_z[4][DD];                         // 2 KB

    // ---- prologue: V_w DMA (linear dest; ws copy pre-swizzled) ----
    {
        const char* __restrict__ wg = (const char*)Vw_bf;
#pragma unroll
        for (int i = 0; i < 8; ++i) {
            __builtin_amdgcn_global_load_lds(
                (const void*)(wg + wv * 8192 + i * 1024 + lane * 16),
                (void*)(s_vw + wv * 8192 + i * 1024), 16, 0, 0);
        }
    }
    // ---- stage tile 0 (cooperative): f32 loads -> cvt -> swizzled write ----
    float4 hreg[8];
    {
        const float4* __restrict__ Hg =
            reinterpret_cast<const float4*>(H + (size_t)base_row * DD);
#pragma unroll
        for (int i = 0; i < 8; ++i) hreg[i] = Hg[i * 256 + tid];
#pragma unroll
        for (int i = 0; i < 8; ++i) {
            bf16x4 r;
            r[0] = (__bf16)hreg[i].x; r[1] = (__bf16)hreg[i].y;
            r[2] = (__bf16)hreg[i].z; r[3] = (__bf16)hreg[i].w;
            const int off = (i * 256 + tid) * 8;   // byte in 16 KB tile
            const int row = off >> 8;              // 256 B per bf16 row
            *reinterpret_cast<bf16x4*>(s_h[0] + (off ^ ((row & 7) << 4))) = r;
        }
    }
    __syncthreads();  // drains V_w DMA vmcnt + tile-0 writes

    // hoisted per-lane epilogue constants
    const float cval = cptr[0];
    float biasv[8], vvv[8];
#pragma unroll
    for (int nt = 0; nt < 8; ++nt) {
        const int col = nt * 16 + cl;
        biasv[nt] = Vb[col] + fkp[b * DD + col];
        vvv[nt]   = vvec[col];
    }

    const int ra   = wv * 16 + cl;
    const int swzA = (cl & 7) << 4;  // (ra&7)<<4, wv*16 ≡ 0 mod 8
    f32x4 zlo[4], zhi[4];            // z accum: d = kk*32 + kg*8 + {0..3, 4..7}
#pragma unroll
    for (int kk = 0; kk < 4; ++kk) {
        zlo[kk] = (f32x4){0.f, 0.f, 0.f, 0.f};
        zhi[kk] = (f32x4){0.f, 0.f, 0.f, 0.f};
    }

    for (int t = 0; t < NT; ++t) {
        const int cur    = t & 1;
        const int grow0  = base_row + t * RPT;
        const int myrow0 = grow0 + wv * 16;

        // ---- prefetch next tile's f32 rows (cooperative; used at tile end) ----
        if (t + 1 < NT) {
            const float4* __restrict__ Hn =
                reinterpret_cast<const float4*>(H + (size_t)(grow0 + RPT) * DD);
#pragma unroll
            for (int i = 0; i < 8; ++i) hreg[i] = Hn[i * 256 + tid];
        }
        const float mfl = (float)mask[myrow0 + cl];

        // ---- A-frags (own rows) as uint4 + bf16 view ----
        uint4  au[4];
        bf16x8 af[4];
#pragma unroll
        for (int kk = 0; kk < 4; ++kk) {
            const int abyte = ra * 256 + kk * 64 + kg * 16;
            au[kk] = *reinterpret_cast<const uint4*>(s_h[cur] + (abyte ^ swzA));
            af[kk] = __builtin_bit_cast(bf16x8, au[kk]);
        }

        // ---- GEMM: own 16 rows x 128 cols ----
        f32x4 acc[8];
#pragma unroll
        for (int nt = 0; nt < 8; ++nt) acc[nt] = (f32x4){0.f, 0.f, 0.f, 0.f};
#pragma unroll
        for (int kk = 0; kk < 4; ++kk) {
#pragma unroll
            for (int nt = 0; nt < 8; ++nt) {
                const int rb    = nt * 16 + cl;
                const int bbyte = (rb * 256 + kk * 64 + kg * 16) ^ ((rb & 7) << 4);
                bf16x8 bfr = *reinterpret_cast<const bf16x8*>(s_vw + bbyte);
                acc[nt] = __builtin_amdgcn_mfma_f32_16x16x32_bf16(af[kk], bfr, acc[nt], 0, 0, 0);
            }
        }

        // ---- epilogue: tanh, v-weighted row-sum, butterfly, e' ----
        float part[4] = {0.f, 0.f, 0.f, 0.f};
#pragma unroll
        for (int nt = 0; nt < 8; ++nt) {
#pragma unroll
            for (int j = 0; j < 4; ++j)
                part[j] = fmaf(fast_tanh(acc[nt][j] + biasv[nt]), vvv[nt], part[j]);
        }
#pragma unroll
        for (int off = 1; off < 16; off <<= 1) {
#pragma unroll
            for (int j = 0; j < 4; ++j) part[j] += __shfl_xor(part[j], off);
        }
        float epj[4];  // e' of rows myrow0 + kg*4 + j, valid across quadrant kg
#pragma unroll
        for (int j = 0; j < 4; ++j) {
            const float mv = __shfl(mfl, kg * 4 + j);
            const float x  = fminf(fmaxf(cval + part[j], -15.f), 15.f);
            epj[j] = __expf(x * mv - 15.f) * mv;
        }
        if (cl == 0) {
#pragma unroll
            for (int j = 0; j < 4; ++j) eout[myrow0 + kg * 4 + j] = epj[j];
        }

        // ---- z accumulate from A-fragment registers (row cl's 32 cols) ----
        const float er0 = __shfl(epj[0], (cl >> 2) << 4);
        const float er1 = __shfl(epj[1], (cl >> 2) << 4);
        const float er2 = __shfl(epj[2], (cl >> 2) << 4);
        const float er3 = __shfl(epj[3], (cl >> 2) << 4);
        const int sel = cl & 3;
        const float e_cl = sel == 0 ? er0 : (sel == 1 ? er1 : (sel == 2 ? er2 : er3));
#pragma unroll
        for (int kk = 0; kk < 4; ++kk) {
            zlo[kk][0] = fmaf(e_cl, bf_at_lo16(au[kk].x), zlo[kk][0]);
            zlo[kk][1] = fmaf(e_cl, bf_at_hi16(au[kk].x), zlo[kk][1]);
            zlo[kk][2] = fmaf(e_cl, bf_at_lo16(au[kk].y), zlo[kk][2]);
            zlo[kk][3] = fmaf(e_cl, bf_at_hi16(au[kk].y), zlo[kk][3]);
            zhi[kk][0] = fmaf(e_cl, bf_at_lo16(au[kk].z), zhi[kk][0]);
            zhi[kk][1] = fmaf(e_cl, bf_at_hi16(au[kk].z), zhi[kk][1]);
            zhi[kk][2] = fmaf(e_cl, bf_at_lo16(au[kk].w), zhi[kk][2]);
            zhi[kk][3] = fmaf(e_cl, bf_at_hi16(au[kk].w), zhi[kk][3]);
        }

        // ---- stage next tile into other buffer, then the ONE barrier ----
        if (t + 1 < NT) {
#pragma unroll
            for (int i = 0; i < 8; ++i) {
                bf16x4 r;
                r[0] = (__bf16)hreg[i].x; r[1] = (__bf16)hreg[i].y;
                r[2] = (__bf16)hreg[i].z; r[3] = (__bf16)hreg[i].w;
                const int off = (i * 256 + tid) * 8;
                const int row = off >> 8;
                *reinterpret_cast<bf16x4*>(s_h[cur ^ 1] + (off ^ ((row & 7) << 4))) = r;
            }
        }
        __syncthreads();
    }

    // ---- final z reduce over the 16 cl-lanes, then cross-wave combine ----
#pragma unroll
    for (int off = 1; off < 16; off <<= 1) {
#pragma unroll
        for (int kk = 0; kk < 4; ++kk) {
#pragma unroll
            for (int j = 0; j < 4; ++j) {
                zlo[kk][j] += __shfl_xor(zlo[kk][j], off);
                zhi[kk][j] += __shfl_xor(zhi[kk][j], off);
            }
        }
    }
    if (cl == 0) {
#pragma unroll
        for (int kk = 0; kk < 4; ++kk) {
#pragma unroll
            for (int j = 0; j < 4; ++j) {
                s_z[wv][kk * 32 + kg * 8 + j]     = zlo[kk][j];
                s_z[wv][kk * 32 + kg * 8 + 4 + j] = zhi[kk][j];
            }
        }
    }
    __syncthreads();
    if (tid < DD) {
        zpart[(size_t)blockIdx.x * DD + tid] =
            (s_z[0][tid] + s_z[1][tid]) + (s_z[2][tid] + s_z[3][tid]);
    }
}

// ---------------------------------------------------------------------------
// Kernel 3 (fused): per-b denom + normalize beta + final z.
// denom = sum(e') + 1e-6 * e^{gmax-15};
// e^{gmax-15} = any_masked ? max(max e', e^-15) : max e'
// ---------------------------------------------------------------------------
__global__ __launch_bounds__(256) void denom_z_kernel(
    float* __restrict__ eout, const int* __restrict__ mask,
    const float* __restrict__ zpart, float* __restrict__ out_z) {
    const int b = blockIdx.x, tid = threadIdx.x;
    float* __restrict__ e = eout + (size_t)b * TT;
    const int* __restrict__ mrow = mask + (size_t)b * TT;
    __shared__ float sE[256], sM[256];
    __shared__ int sA[256];

    float E = 0.f, M = 0.f;
    int any0 = 0;
    for (int t = tid; t < TT; t += 256) {
        float ep = e[t];
        E += ep;
        M = fmaxf(M, ep);
        any0 |= (mrow[t] == 0);
    }
    sE[tid] = E; sM[tid] = M; sA[tid] = any0;
    __syncthreads();
    for (int s = 128; s > 0; s >>= 1) {
        if (tid < s) {
            sE[tid] += sE[tid + s];
            sM[tid] = fmaxf(sM[tid], sM[tid + s]);
            sA[tid] |= sA[tid + s];
        }
        __syncthreads();
    }
    const float scale = sA[0] ? fmaxf(sM[0], 3.0590232e-7f /*e^-15*/) : sM[0];
    const float dn = sE[0] + 1e-6f * scale;
    const float inv = 1.f / dn;

    for (int t = tid; t < TT; t += 256) e[t] *= inv;

    if (tid < DD) {
        const float* __restrict__ zp = zpart + (size_t)b * BPB * DD + tid;
        float s = 0.f;
#pragma unroll
        for (int cc = 0; cc < BPB; ++cc) s += zp[cc * DD];
        out_z[b * DD + tid] = s * inv;
    }
}

// ---------------------------------------------------------------------------
extern "C" void kernel_launch(void* const* d_in, const int* in_sizes, int n_in,
                              void* d_out, int out_size, void* d_ws, size_t ws_size,
                              hipStream_t stream) {
    const float* H     = (const float*)d_in[0]; // [B,T,D] f32
    const int*   mask  = (const int*)d_in[1];   // [B,T] int32
    const float* h_tm1 = (const float*)d_in[2]; // [B,D] f32
    const float* V_w   = (const float*)d_in[3]; // [D,D] f32
    const float* V_b   = (const float*)d_in[4]; // [D] f32
    const float* Wa_w  = (const float*)d_in[5]; // [D,D] f32
    const float* Wa_b  = (const float*)d_in[6]; // [D] f32
    const float* v     = (const float*)d_in[7]; // [D] f32
    const float* c     = (const float*)d_in[8]; // [1] f32

    float* out_z    = (float*)d_out;           // B*D f32
    float* out_beta = (float*)d_out + BB * DD; // B*T f32

    float* ws     = (float*)d_ws;
    float* fkp    = ws;                       // B*D     =  8192 f32
    float* zpart  = fkp + BB * DD;            // NBLK*DD = 65536 f32
    __bf16* Vw_bf = (__bf16*)(zpart + NBLK * DD); // D*D bf16 (pre-swizzled)

    prep_kernel<<<BB, 256, 0, stream>>>(V_w, Wa_w, Wa_b, h_tm1, Vw_bf, fkp);
    beta_z_kernel<<<NBLK, 256, 0, stream>>>(H, Vw_bf, V_b, fkp, v, c, mask,
                                            out_beta, zpart);
    denom_z_kernel<<<BB, 256, 0, stream>>>(out_beta, mask, zpart, out_z);
}